// Round 10
// baseline (144.414 us; speedup 1.0000x reference)
//
#include <hip/hip_runtime.h>
#include <hip/hip_bf16.h>

// Relative (Transformer-XL) multi-head attention, MI355X gfx950.
// B=8, T=1024, H=8, d=64, D_MODEL=512, W=2047. Output f32.
//
// Round 10:
//  - attn: QBLK=128 (512 blocks, 2 q-subtiles/block). bk/bv fragment reads
//    shared across subtiles (read once, MFMA twice); 192-row pos window with
//    9 shared fragment reads for 10 MFMA-sets; probs into the dead window
//    region; full window restage (static frag indices). launch_bounds(256,2)
//    (~210 VGPR, no spill; 512 blocks = exactly 2/CU). One head per XCD.
//  - transpose5: LDS-tiled coalesced (was scalar scatter, ~9us -> ~2us)
//  - pos projection folded into qkv_gemm128 as nt==12 (one fewer launch)

typedef __attribute__((ext_vector_type(8))) short short8;
typedef __attribute__((ext_vector_type(4))) float float4v;
typedef __fp16 h2v __attribute__((ext_vector_type(2)));

__device__ __forceinline__ unsigned short f2bf(float f) {
  union { float f; unsigned u; } x; x.f = f;
  unsigned r = x.u + 0x7FFFu + ((x.u >> 16) & 1u);
  return (unsigned short)(r >> 16);
}
__device__ __forceinline__ int pk2h(float a, float b) {
  union { h2v h; int i; } c; c.h = __builtin_amdgcn_cvt_pkrtz(a, b);
  return c.i;
}
__device__ __forceinline__ float h_lo(int w) {
  union { int i; h2v h; } c; c.i = w; return (float)c.h.x;
}
__device__ __forceinline__ float h_hi(int w) {
  union { int i; h2v h; } c; c.i = w; return (float)c.h.y;
}

// ---------- conversion kernels ----------
__global__ void cvt_bf16_kernel(const float* __restrict__ in,
                                unsigned short* __restrict__ out, int n4) {
  int i = blockIdx.x * blockDim.x + threadIdx.x;
  if (i < n4) {
    float4 f = ((const float4*)in)[i];
    ushort4 r;
    r.x = f2bf(f.x); r.y = f2bf(f.y); r.z = f2bf(f.z); r.w = f2bf(f.w);
    ((ushort4*)out)[i] = r;
  }
}

// 5x 512x512 transpose+cvt, LDS-tiled (coalesced loads AND stores)
__global__ void transpose_cvt5_kernel(const float* __restrict__ Wq,
                                      const float* __restrict__ Wk,
                                      const float* __restrict__ Wv,
                                      const float* __restrict__ Wp,
                                      const float* __restrict__ Wo,
                                      unsigned short* __restrict__ dst) {
  __shared__ float T[64][65];
  int y = blockIdx.y;
  const float* w = (y == 0) ? Wq : (y == 1) ? Wk : (y == 2) ? Wv : (y == 3) ? Wp : Wo;
  unsigned short* wt = dst + (size_t)y * 262144;
  int bx = blockIdx.x;                       // 64 tiles of 64x64
  int r0 = (bx >> 3) * 64, c0 = (bx & 7) * 64;
  int tid = threadIdx.x;
  int row = tid >> 2, cq = (tid & 3) * 16;
  const float* src = w + (size_t)(r0 + row) * 512 + c0 + cq;
#pragma unroll
  for (int j = 0; j < 4; ++j) {
    float4 f = *(const float4*)(src + j * 4);
    T[row][cq + j * 4 + 0] = f.x; T[row][cq + j * 4 + 1] = f.y;
    T[row][cq + j * 4 + 2] = f.z; T[row][cq + j * 4 + 3] = f.w;
  }
  __syncthreads();
  unsigned short tmp[16];
#pragma unroll
  for (int j = 0; j < 16; ++j) tmp[j] = f2bf(T[cq + j][row]);
  unsigned short* op = wt + (size_t)(c0 + row) * 512 + r0 + cq;
  *(uint4*)op       = *(uint4*)tmp;
  *(uint4*)(op + 8) = *(uint4*)(tmp + 8);
}

// ---------- 128x128-tile projection GEMM (QKV + pos) ----------
// nt 0..3: Q -> QU/QV; nt 4..7: K; nt 8..11: V -> Vt transposed;
// nt 12: pos projection (A=peb, B=wpt, C=pb; mt encodes pmt/pnt).
__global__ __launch_bounds__(256, 2) void qkv_gemm128(
    const unsigned short* __restrict__ A,
    const unsigned short* __restrict__ Bt,
    const float* __restrict__ bq,
    const float* __restrict__ uvec,
    const float* __restrict__ vvec,
    unsigned short* __restrict__ QU, unsigned short* __restrict__ QV,
    unsigned short* __restrict__ Kb, unsigned short* __restrict__ Vt,
    const unsigned short* __restrict__ Pe,   // peb (2048x512)
    const unsigned short* __restrict__ Wpt,  // Wp^T
    unsigned short* __restrict__ Pb) {       // pos out (2048x512)
  __shared__ __align__(16) unsigned short lds[2 * 128 * 72];
  unsigned short (*As)[72] = (unsigned short(*)[72])lds;
  unsigned short (*Bs)[72] = (unsigned short(*)[72])(lds + 128 * 72);
  int mt = blockIdx.x, nt = blockIdx.y;
  int tid = threadIdx.x;
  int lane = tid & 63, wave = tid >> 6;
  int l15 = lane & 15, g = lane >> 4;
  int wr = (wave >> 1) << 6, wc = (wave & 1) << 6;
  int sr = tid >> 1, sc = (tid & 1) << 5;

  const unsigned short* Ap;
  const unsigned short* Bp;
  if (nt < 12) {
    Ap = A + (size_t)(mt * 128 + sr) * 512 + sc;
    Bp = Bt + (size_t)(nt * 128 + sr) * 512 + sc;
  } else {
    Ap = Pe + (size_t)((mt & 15) * 128 + sr) * 512 + sc;
    Bp = Wpt + (size_t)((mt >> 4) * 128 + sr) * 512 + sc;
  }

  uint4 a0 = *(const uint4*)Ap,        a1 = *(const uint4*)(Ap + 8);
  uint4 a2 = *(const uint4*)(Ap + 16), a3 = *(const uint4*)(Ap + 24);
  uint4 b0 = *(const uint4*)Bp,        b1 = *(const uint4*)(Bp + 8);
  uint4 b2 = *(const uint4*)(Bp + 16), b3 = *(const uint4*)(Bp + 24);

  float4v acc[4][4] = {};
  for (int kt = 0; kt < 8; ++kt) {
    *(uint4*)&As[sr][sc]      = a0; *(uint4*)&As[sr][sc + 8]  = a1;
    *(uint4*)&As[sr][sc + 16] = a2; *(uint4*)&As[sr][sc + 24] = a3;
    *(uint4*)&Bs[sr][sc]      = b0; *(uint4*)&Bs[sr][sc + 8]  = b1;
    *(uint4*)&Bs[sr][sc + 16] = b2; *(uint4*)&Bs[sr][sc + 24] = b3;
    __syncthreads();
    if (kt < 7) {
      const unsigned short* ap = Ap + (kt + 1) * 64;
      a0 = *(const uint4*)ap;        a1 = *(const uint4*)(ap + 8);
      a2 = *(const uint4*)(ap + 16); a3 = *(const uint4*)(ap + 24);
      const unsigned short* bp = Bp + (kt + 1) * 64;
      b0 = *(const uint4*)bp;        b1 = *(const uint4*)(bp + 8);
      b2 = *(const uint4*)(bp + 16); b3 = *(const uint4*)(bp + 24);
    }
#pragma unroll
    for (int ks = 0; ks < 2; ++ks) {
      short8 af[4], bf[4];
#pragma unroll
      for (int fm = 0; fm < 4; ++fm)
        af[fm] = *(const short8*)&As[wr + fm * 16 + l15][ks * 32 + g * 8];
#pragma unroll
      for (int fn = 0; fn < 4; ++fn)
        bf[fn] = *(const short8*)&Bs[wc + fn * 16 + l15][ks * 32 + g * 8];
#pragma unroll
      for (int fm = 0; fm < 4; ++fm)
#pragma unroll
        for (int fn = 0; fn < 4; ++fn)
          acc[fm][fn] = __builtin_amdgcn_mfma_f32_16x16x32_bf16(
              af[fm], bf[fn], acc[fm][fn], 0, 0, 0);
    }
    if (kt < 7) __syncthreads();
  }

  if (nt < 4) {
#pragma unroll
    for (int fn = 0; fn < 4; ++fn) {
      int col = nt * 128 + wc + fn * 16 + l15;
      float bs = bq[col], uu = uvec[col], vv = vvec[col];
#pragma unroll
      for (int fm = 0; fm < 4; ++fm) {
        int row = mt * 128 + wr + fm * 16 + 4 * g;
#pragma unroll
        for (int r = 0; r < 4; ++r) {
          size_t idx = (size_t)(row + r) * 512 + col;
          float base = acc[fm][fn][r] + bs;
          QU[idx] = f2bf(base + uu);
          QV[idx] = f2bf(base + vv);
        }
      }
    }
  } else if (nt < 8) {
#pragma unroll
    for (int fn = 0; fn < 4; ++fn) {
      int col = (nt - 4) * 128 + wc + fn * 16 + l15;
#pragma unroll
      for (int fm = 0; fm < 4; ++fm) {
        int row = mt * 128 + wr + fm * 16 + 4 * g;
#pragma unroll
        for (int r = 0; r < 4; ++r)
          Kb[(size_t)(row + r) * 512 + col] = f2bf(acc[fm][fn][r]);
      }
    }
  } else if (nt < 12) {
    // V: transpose 128x128 tile through LDS, write Vt[b][h][d][s]
    __syncthreads();
    unsigned short (*T)[136] = (unsigned short(*)[136])lds;
#pragma unroll
    for (int fm = 0; fm < 4; ++fm)
#pragma unroll
      for (int fn = 0; fn < 4; ++fn)
#pragma unroll
        for (int r = 0; r < 4; ++r)
          T[wc + fn * 16 + l15][wr + fm * 16 + 4 * g + r] = f2bf(acc[fm][fn][r]);
    __syncthreads();
    int c2 = tid >> 1, sh = (tid & 1) << 6;
    int gcol = (nt - 8) * 128 + c2;
    int bb = mt >> 3, s0 = (mt & 7) * 128;
    unsigned short* op = Vt +
        ((size_t)((bb * 8 + (gcol >> 6)) * 64 + (gcol & 63))) * 1024 + s0 + sh;
#pragma unroll
    for (int j = 0; j < 8; ++j)
      *(uint4*)(op + j * 8) = *(uint4*)&T[c2][sh + j * 8];
  } else {
#pragma unroll
    for (int fn = 0; fn < 4; ++fn) {
      int col = (mt >> 4) * 128 + wc + fn * 16 + l15;
#pragma unroll
      for (int fm = 0; fm < 4; ++fm) {
        int row = (mt & 15) * 128 + wr + fm * 16 + 4 * g;
#pragma unroll
        for (int r = 0; r < 4; ++r)
          Pb[(size_t)(row + r) * 512 + col] = f2bf(acc[fm][fn][r]);
      }
    }
  }
}

// ---------- 128x128-tile GEMM, f32 out + bias (out projection) ----------
__global__ __launch_bounds__(256, 2) void gemm128f(
    const unsigned short* __restrict__ A,
    const unsigned short* __restrict__ Bt,
    const float* __restrict__ bias,
    float* __restrict__ Cf) {
  __shared__ __align__(16) unsigned short lds[2 * 128 * 72];
  unsigned short (*As)[72] = (unsigned short(*)[72])lds;
  unsigned short (*Bs)[72] = (unsigned short(*)[72])(lds + 128 * 72);
  int mt = blockIdx.x, nt = blockIdx.y;
  int tid = threadIdx.x;
  int lane = tid & 63, wave = tid >> 6;
  int l15 = lane & 15, g = lane >> 4;
  int wr = (wave >> 1) << 6, wc = (wave & 1) << 6;
  int sr = tid >> 1, sc = (tid & 1) << 5;

  const unsigned short* Ap = A + (size_t)(mt * 128 + sr) * 512 + sc;
  const unsigned short* Bp = Bt + (size_t)(nt * 128 + sr) * 512 + sc;

  uint4 a0 = *(const uint4*)Ap,        a1 = *(const uint4*)(Ap + 8);
  uint4 a2 = *(const uint4*)(Ap + 16), a3 = *(const uint4*)(Ap + 24);
  uint4 b0 = *(const uint4*)Bp,        b1 = *(const uint4*)(Bp + 8);
  uint4 b2 = *(const uint4*)(Bp + 16), b3 = *(const uint4*)(Bp + 24);

  float4v acc[4][4] = {};
  for (int kt = 0; kt < 8; ++kt) {
    *(uint4*)&As[sr][sc]      = a0; *(uint4*)&As[sr][sc + 8]  = a1;
    *(uint4*)&As[sr][sc + 16] = a2; *(uint4*)&As[sr][sc + 24] = a3;
    *(uint4*)&Bs[sr][sc]      = b0; *(uint4*)&Bs[sr][sc + 8]  = b1;
    *(uint4*)&Bs[sr][sc + 16] = b2; *(uint4*)&Bs[sr][sc + 24] = b3;
    __syncthreads();
    if (kt < 7) {
      const unsigned short* ap = Ap + (kt + 1) * 64;
      a0 = *(const uint4*)ap;        a1 = *(const uint4*)(ap + 8);
      a2 = *(const uint4*)(ap + 16); a3 = *(const uint4*)(ap + 24);
      const unsigned short* bp = Bp + (kt + 1) * 64;
      b0 = *(const uint4*)bp;        b1 = *(const uint4*)(bp + 8);
      b2 = *(const uint4*)(bp + 16); b3 = *(const uint4*)(bp + 24);
    }
#pragma unroll
    for (int ks = 0; ks < 2; ++ks) {
      short8 af[4], bf[4];
#pragma unroll
      for (int fm = 0; fm < 4; ++fm)
        af[fm] = *(const short8*)&As[wr + fm * 16 + l15][ks * 32 + g * 8];
#pragma unroll
      for (int fn = 0; fn < 4; ++fn)
        bf[fn] = *(const short8*)&Bs[wc + fn * 16 + l15][ks * 32 + g * 8];
#pragma unroll
      for (int fm = 0; fm < 4; ++fm)
#pragma unroll
        for (int fn = 0; fn < 4; ++fn)
          acc[fm][fn] = __builtin_amdgcn_mfma_f32_16x16x32_bf16(
              af[fm], bf[fn], acc[fm][fn], 0, 0, 0);
    }
    if (kt < 7) __syncthreads();
  }
#pragma unroll
  for (int fn = 0; fn < 4; ++fn) {
    int col = nt * 128 + wc + fn * 16 + l15;
    float bs = bias[col];
#pragma unroll
    for (int fm = 0; fm < 4; ++fm) {
      int row = mt * 128 + wr + fm * 16 + 4 * g;
#pragma unroll
      for (int r = 0; r < 4; ++r)
        Cf[(size_t)(row + r) * 512 + col] = acc[fm][fn][r] + bs;
    }
  }
}

// ---------- fused relative attention, QBLK=128 ----------
// grid 512 (one head per XCD), 256 threads (4 waves; each wave owns 32
// q-rows = 16 per subtile m). 192-row pos window, full restage per s-tile.
// Window frags for subtile m, wave w: m=1 -> 3-w..7-w, m=0 -> 7-w..11-w
// (frag 7-w shared). Probs overwrite the dead window rows 0..127.
__global__ __launch_bounds__(256, 2) void attn_kernel(
    const unsigned short* __restrict__ QU,  // (B*T,512) bf16 = q+bq+u
    const unsigned short* __restrict__ QV,  // (B*T,512) bf16 = q+bq+v
    const unsigned short* __restrict__ K,   // (B*T,512) bf16
    const unsigned short* __restrict__ Vt,  // [b][h][d][s] bf16
    const unsigned short* __restrict__ P,   // (2047,512) bf16 (2048 alloc)
    unsigned short* __restrict__ O) {       // (B*T,512) bf16
  __shared__ __align__(16) unsigned short k_s[64][72];
  __shared__ __align__(16) unsigned short vt_s[64][72];
  __shared__ __align__(16) unsigned short win_s[192 * 72];

  // XCD swizzle: 512 blocks = 8 XCDs x 64; each XCD owns one head h.
  int pid = blockIdx.x;
  int wid = (pid & 7) * 64 + (pid >> 3);
  int tt = wid & 7, b = (wid >> 3) & 7, h = wid >> 6;
  int t0 = tt * 128;
  int tid = threadIdx.x, lane = tid & 63, wave = tid >> 6;
  int lr = tid >> 2, lc = (tid & 3) << 4;
  int l15 = lane & 15, g = lane >> 4;
  int w16 = wave * 16;
  int wrow = tid >> 3, wcol = (tid & 7) << 3;   // window stage map
  int C = 3 - wave;

  // Q fragments (both subtiles) straight from global, held for the block
  short8 aqu[2][2], aqv[2][2];
#pragma unroll
  for (int m = 0; m < 2; ++m) {
    size_t qoff = (size_t)(b * 1024 + t0 + 64 * m + w16 + l15) * 512 + h * 64 + g * 8;
    aqu[m][0] = *(const short8*)(QU + qoff);
    aqu[m][1] = *(const short8*)(QU + qoff + 32);
    aqv[m][0] = *(const short8*)(QV + qoff);
    aqv[m][1] = *(const short8*)(QV + qoff + 32);
  }

  const unsigned short* Kbase = K + (size_t)(b * 1024) * 512 + h * 64;
  const unsigned short* Vbase = Vt + (size_t)((b * 8 + h) * 64) * 1024;
  const unsigned short* Pbase = P + h * 64;

  float4v accO[2][4] = {};
  float l_r[2][4] = {};

  // -------- prologue: stage tile 0 --------
  {
    const unsigned short* kp = Kbase + (size_t)lr * 512 + lc;
    uint4 k0 = *(const uint4*)kp, k1 = *(const uint4*)(kp + 8);
    const unsigned short* vp = Vbase + (size_t)lr * 1024 + lc;
    uint4 v0 = *(const uint4*)vp, v1 = *(const uint4*)(vp + 8);
    int wb = 896 - t0;                       // >= 0 (t0 <= 896)
    uint4 wv[6];
#pragma unroll
    for (int c = 0; c < 6; ++c)
      wv[c] = *(const uint4*)(Pbase + (size_t)(wb + c * 32 + wrow) * 512 + wcol);
    *(uint4*)&k_s[lr][lc]      = k0; *(uint4*)&k_s[lr][lc + 8]  = k1;
    *(uint4*)&vt_s[lr][lc]     = v0; *(uint4*)&vt_s[lr][lc + 8] = v1;
#pragma unroll
    for (int c = 0; c < 6; ++c)
      *(uint4*)&win_s[(c * 32 + wrow) * 72 + wcol] = wv[c];
  }
  __syncthreads();

  uint4 pk0, pk1, pv0, pv1, pw[6];
  for (int st = 0; st < 16; ++st) {
    // issue next tile's global loads (latency hides under compute)
    if (st < 15) {
      int s0n = (st + 1) * 64;
      const unsigned short* kp = Kbase + (size_t)(s0n + lr) * 512 + lc;
      pk0 = *(const uint4*)kp; pk1 = *(const uint4*)(kp + 8);
      const unsigned short* vp = Vbase + (size_t)lr * 1024 + s0n + lc;
      pv0 = *(const uint4*)vp; pv1 = *(const uint4*)(vp + 8);
      int wb = s0n - t0 + 896;
#pragma unroll
      for (int c = 0; c < 6; ++c) {
        int w = wb + c * 32 + wrow; if (w > 2046) w = 2046;
        pw[c] = *(const uint4*)(Pbase + (size_t)w * 512 + wcol);
      }
    }

    // content scores (both subtiles share bk) + 9 window fragment reads
    float4v accS[2][4] = {}; float4v accP[2][5] = {};
#pragma unroll
    for (int ks = 0; ks < 2; ++ks) {
#pragma unroll
      for (int fn = 0; fn < 4; ++fn) {
        short8 bk = *(const short8*)&k_s[fn * 16 + l15][ks * 32 + g * 8];
        accS[0][fn] = __builtin_amdgcn_mfma_f32_16x16x32_bf16(aqu[0][ks], bk, accS[0][fn], 0, 0, 0);
        accS[1][fn] = __builtin_amdgcn_mfma_f32_16x16x32_bf16(aqu[1][ks], bk, accS[1][fn], 0, 0, 0);
      }
#pragma unroll
      for (int j = 0; j < 9; ++j) {
        short8 bp = *(const short8*)&win_s[((C + j) * 16 + l15) * 72 + ks * 32 + g * 8];
        if (j <= 4)
          accP[1][j] = __builtin_amdgcn_mfma_f32_16x16x32_bf16(aqv[1][ks], bp, accP[1][j], 0, 0, 0);
        if (j >= 4)
          accP[0][j - 4] = __builtin_amdgcn_mfma_f32_16x16x32_bf16(aqv[0][ks], bp, accP[0][j - 4], 0, 0, 0);
      }
    }

    // relative shift via packed-f16 lane rotation (per subtile)
#pragma unroll
    for (int m = 0; m < 2; ++m)
#pragma unroll
      for (int r = 0; r < 4; ++r) {
        int W0 = pk2h(accP[m][0][r], accP[m][1][r]);
        int W1 = pk2h(accP[m][1][r], accP[m][2][r]);
        int W2 = pk2h(accP[m][2][r], accP[m][3][r]);
        int W3 = pk2h(accP[m][3][r], accP[m][4][r]);
        int srcLane = (lane & 48) | ((l15 - 4 * g - r - 1) & 15);
        int carry = (l15 >= 4 * g + r + 1);
        int x0 = __shfl(W0, srcLane), x1 = __shfl(W1, srcLane);
        int x2 = __shfl(W2, srcLane), x3 = __shfl(W3, srcLane);
        int wa = carry ? x1 : x0;
        int wb2 = carry ? x3 : x2;
        accS[m][0][r] = (accS[m][0][r] + h_lo(wa)) * 0.125f;
        accS[m][1][r] = (accS[m][1][r] + h_hi(wa)) * 0.125f;
        accS[m][2][r] = (accS[m][2][r] + h_lo(wb2)) * 0.125f;
        accS[m][3][r] = (accS[m][3][r] + h_hi(wb2)) * 0.125f;
      }

    __syncthreads();     // B3: all waves done reading window/k_s

    // no-max softmax: probs into dead window rows [64m + w16, +16)
#pragma unroll
    for (int m = 0; m < 2; ++m)
#pragma unroll
      for (int r = 0; r < 4; ++r) {
        float rs = 0.f;
#pragma unroll
        for (int fn = 0; fn < 4; ++fn) {
          float e = __expf(accS[m][fn][r] - 8.0f);
          win_s[(64 * m + w16 + 4 * g + r) * 72 + fn * 16 + l15] = f2bf(e);
          rs += e;
        }
        l_r[m][r] += rs;
      }

    // PV: bv shared across subtiles
#pragma unroll
    for (int ks = 0; ks < 2; ++ks) {
      short8 bv[4];
#pragma unroll
      for (int fn = 0; fn < 4; ++fn)
        bv[fn] = *(const short8*)&vt_s[fn * 16 + l15][ks * 32 + g * 8];
#pragma unroll
      for (int m = 0; m < 2; ++m) {
        short8 ap = *(const short8*)&win_s[(64 * m + w16 + l15) * 72 + ks * 32 + g * 8];
#pragma unroll
        for (int fn = 0; fn < 4; ++fn)
          accO[m][fn] = __builtin_amdgcn_mfma_f32_16x16x32_bf16(ap, bv[fn], accO[m][fn], 0, 0, 0);
      }
    }

    if (st < 15) {
      __syncthreads();   // B1: probs + vt_s reads done everywhere
      *(uint4*)&k_s[lr][lc]      = pk0; *(uint4*)&k_s[lr][lc + 8]  = pk1;
      *(uint4*)&vt_s[lr][lc]     = pv0; *(uint4*)&vt_s[lr][lc + 8] = pv1;
#pragma unroll
      for (int c = 0; c < 6; ++c)
        *(uint4*)&win_s[(c * 32 + wrow) * 72 + wcol] = pw[c];
      __syncthreads();   // B2: staging visible
    }
  }

  // epilogue
#pragma unroll
  for (int m = 0; m < 2; ++m) {
    float rinv[4];
#pragma unroll
    for (int r = 0; r < 4; ++r) {
      float l = l_r[m][r];
      l += __shfl_xor(l, 1); l += __shfl_xor(l, 2);
      l += __shfl_xor(l, 4); l += __shfl_xor(l, 8);
      rinv[r] = 1.0f / l;
    }
#pragma unroll
    for (int fn = 0; fn < 4; ++fn) {
      int dcol = fn * 16 + l15;
#pragma unroll
      for (int r = 0; r < 4; ++r) {
        int row = t0 + 64 * m + w16 + 4 * g + r;
        float o = accO[m][fn][r] * rinv[r];
        O[(size_t)(b * 1024 + row) * 512 + h * 64 + dcol] = f2bf(o);
      }
    }
  }
}

// ---------- host ----------
extern "C" void kernel_launch(void* const* d_in, const int* in_sizes, int n_in,
                              void* d_out, int out_size, void* d_ws, size_t ws_size,
                              hipStream_t stream) {
  const float* x       = (const float*)d_in[0];
  const float* pos_emb = (const float*)d_in[1];
  const float* Wq      = (const float*)d_in[2];
  const float* bq      = (const float*)d_in[3];
  const float* Wk      = (const float*)d_in[4];
  const float* Wv      = (const float*)d_in[5];
  const float* Wp      = (const float*)d_in[6];
  const float* Wo      = (const float*)d_in[7];
  const float* bo      = (const float*)d_in[8];
  const float* u       = (const float*)d_in[9];
  const float* v       = (const float*)d_in[10];

  char* ws = (char*)d_ws;
  unsigned short* xb   = (unsigned short*)ws; ws += (size_t)8192 * 512 * 2;
  unsigned short* peb  = (unsigned short*)ws; ws += (size_t)2048 * 512 * 2;
  unsigned short* wqkv = (unsigned short*)ws; ws += (size_t)5 * 512 * 512 * 2;
  unsigned short* qub  = (unsigned short*)ws; ws += (size_t)8192 * 512 * 2;
  unsigned short* qvb  = (unsigned short*)ws; ws += (size_t)8192 * 512 * 2;
  unsigned short* kb   = (unsigned short*)ws; ws += (size_t)8192 * 512 * 2;
  unsigned short* vtb  = (unsigned short*)ws; ws += (size_t)8192 * 512 * 2;
  unsigned short* pb   = (unsigned short*)ws; ws += (size_t)2048 * 512 * 2;
  unsigned short* attb = (unsigned short*)ws; ws += (size_t)8192 * 512 * 2;

  cvt_bf16_kernel<<<4096, 256, 0, stream>>>(x, xb, 1048576);
  cvt_bf16_kernel<<<1024, 256, 0, stream>>>(pos_emb, peb, 262016);
  transpose_cvt5_kernel<<<dim3(64, 5), 256, 0, stream>>>(Wq, Wk, Wv, Wp, Wo, wqkv);
  unsigned short* wpt_p = wqkv + (size_t)3 * 262144;
  unsigned short* wot_p = wqkv + (size_t)4 * 262144;

  qkv_gemm128<<<dim3(64, 13), 256, 0, stream>>>(xb, wqkv, bq, u, v,
                                                qub, qvb, kb, vtb,
                                                peb, wpt_p, pb);

  attn_kernel<<<512, 256, 0, stream>>>(qub, qvb, kb, vtb, pb, attb);

  gemm128f<<<dim3(64, 4), 256, 0, stream>>>(attb, wot_p, bo, (float*)d_out);
}

// Round 11
// 122.742 us; speedup vs baseline: 1.1766x; 1.1766x over previous
//
#include <hip/hip_runtime.h>
#include <hip/hip_bf16.h>

// Relative (Transformer-XL) multi-head attention, MI355X gfx950.
// B=8, T=1024, H=8, d=64, D_MODEL=512, W=2047. Output f32.
//
// Round 11 = R9 attn (proven 68.5us) + R10 non-attn pipeline (proven -6us).
//  R10's QBLK=128 attn experiment is concluded: DS-op savings < occupancy
//  loss (blocks/CU 3->2, VGPR 64->112, partial spill). Reverted.
//  - attn: QBLK=64, 5-fragment window trim, circular 128-row window,
//    no-max softmax, f16-packed shift, XCD swizzle, reg prefetch, (256,3)
//  - transpose5: LDS-tiled coalesced
//  - qkv_gemm128: 128^2 tiles, V transposed in epilogue, pos folded (nt=12)
//  - gemm128f: 128^2 out-projection

typedef __attribute__((ext_vector_type(8))) short short8;
typedef __attribute__((ext_vector_type(4))) float float4v;
typedef __fp16 h2v __attribute__((ext_vector_type(2)));

__device__ __forceinline__ unsigned short f2bf(float f) {
  union { float f; unsigned u; } x; x.f = f;
  unsigned r = x.u + 0x7FFFu + ((x.u >> 16) & 1u);
  return (unsigned short)(r >> 16);
}
__device__ __forceinline__ int pk2h(float a, float b) {
  union { h2v h; int i; } c; c.h = __builtin_amdgcn_cvt_pkrtz(a, b);
  return c.i;
}
__device__ __forceinline__ float h_lo(int w) {
  union { int i; h2v h; } c; c.i = w; return (float)c.h.x;
}
__device__ __forceinline__ float h_hi(int w) {
  union { int i; h2v h; } c; c.i = w; return (float)c.h.y;
}

// ---------- conversion kernels ----------
__global__ void cvt_bf16_kernel(const float* __restrict__ in,
                                unsigned short* __restrict__ out, int n4) {
  int i = blockIdx.x * blockDim.x + threadIdx.x;
  if (i < n4) {
    float4 f = ((const float4*)in)[i];
    ushort4 r;
    r.x = f2bf(f.x); r.y = f2bf(f.y); r.z = f2bf(f.z); r.w = f2bf(f.w);
    ((ushort4*)out)[i] = r;
  }
}

// 5x 512x512 transpose+cvt, LDS-tiled (coalesced loads AND stores)
__global__ void transpose_cvt5_kernel(const float* __restrict__ Wq,
                                      const float* __restrict__ Wk,
                                      const float* __restrict__ Wv,
                                      const float* __restrict__ Wp,
                                      const float* __restrict__ Wo,
                                      unsigned short* __restrict__ dst) {
  __shared__ float T[64][65];
  int y = blockIdx.y;
  const float* w = (y == 0) ? Wq : (y == 1) ? Wk : (y == 2) ? Wv : (y == 3) ? Wp : Wo;
  unsigned short* wt = dst + (size_t)y * 262144;
  int bx = blockIdx.x;                       // 64 tiles of 64x64
  int r0 = (bx >> 3) * 64, c0 = (bx & 7) * 64;
  int tid = threadIdx.x;
  int row = tid >> 2, cq = (tid & 3) * 16;
  const float* src = w + (size_t)(r0 + row) * 512 + c0 + cq;
#pragma unroll
  for (int j = 0; j < 4; ++j) {
    float4 f = *(const float4*)(src + j * 4);
    T[row][cq + j * 4 + 0] = f.x; T[row][cq + j * 4 + 1] = f.y;
    T[row][cq + j * 4 + 2] = f.z; T[row][cq + j * 4 + 3] = f.w;
  }
  __syncthreads();
  unsigned short tmp[16];
#pragma unroll
  for (int j = 0; j < 16; ++j) tmp[j] = f2bf(T[cq + j][row]);
  unsigned short* op = wt + (size_t)(c0 + row) * 512 + r0 + cq;
  *(uint4*)op       = *(uint4*)tmp;
  *(uint4*)(op + 8) = *(uint4*)(tmp + 8);
}

// ---------- 128x128-tile projection GEMM (QKV + pos) ----------
// nt 0..3: Q -> QU/QV; nt 4..7: K; nt 8..11: V -> Vt transposed;
// nt 12: pos projection (A=peb, B=wpt, C=pb; mt encodes pmt/pnt).
__global__ __launch_bounds__(256, 2) void qkv_gemm128(
    const unsigned short* __restrict__ A,
    const unsigned short* __restrict__ Bt,
    const float* __restrict__ bq,
    const float* __restrict__ uvec,
    const float* __restrict__ vvec,
    unsigned short* __restrict__ QU, unsigned short* __restrict__ QV,
    unsigned short* __restrict__ Kb, unsigned short* __restrict__ Vt,
    const unsigned short* __restrict__ Pe,   // peb (2048x512)
    const unsigned short* __restrict__ Wpt,  // Wp^T
    unsigned short* __restrict__ Pb) {       // pos out (2048x512)
  __shared__ __align__(16) unsigned short lds[2 * 128 * 72];
  unsigned short (*As)[72] = (unsigned short(*)[72])lds;
  unsigned short (*Bs)[72] = (unsigned short(*)[72])(lds + 128 * 72);
  int mt = blockIdx.x, nt = blockIdx.y;
  int tid = threadIdx.x;
  int lane = tid & 63, wave = tid >> 6;
  int l15 = lane & 15, g = lane >> 4;
  int wr = (wave >> 1) << 6, wc = (wave & 1) << 6;
  int sr = tid >> 1, sc = (tid & 1) << 5;

  const unsigned short* Ap;
  const unsigned short* Bp;
  if (nt < 12) {
    Ap = A + (size_t)(mt * 128 + sr) * 512 + sc;
    Bp = Bt + (size_t)(nt * 128 + sr) * 512 + sc;
  } else {
    Ap = Pe + (size_t)((mt & 15) * 128 + sr) * 512 + sc;
    Bp = Wpt + (size_t)((mt >> 4) * 128 + sr) * 512 + sc;
  }

  uint4 a0 = *(const uint4*)Ap,        a1 = *(const uint4*)(Ap + 8);
  uint4 a2 = *(const uint4*)(Ap + 16), a3 = *(const uint4*)(Ap + 24);
  uint4 b0 = *(const uint4*)Bp,        b1 = *(const uint4*)(Bp + 8);
  uint4 b2 = *(const uint4*)(Bp + 16), b3 = *(const uint4*)(Bp + 24);

  float4v acc[4][4] = {};
  for (int kt = 0; kt < 8; ++kt) {
    *(uint4*)&As[sr][sc]      = a0; *(uint4*)&As[sr][sc + 8]  = a1;
    *(uint4*)&As[sr][sc + 16] = a2; *(uint4*)&As[sr][sc + 24] = a3;
    *(uint4*)&Bs[sr][sc]      = b0; *(uint4*)&Bs[sr][sc + 8]  = b1;
    *(uint4*)&Bs[sr][sc + 16] = b2; *(uint4*)&Bs[sr][sc + 24] = b3;
    __syncthreads();
    if (kt < 7) {
      const unsigned short* ap = Ap + (kt + 1) * 64;
      a0 = *(const uint4*)ap;        a1 = *(const uint4*)(ap + 8);
      a2 = *(const uint4*)(ap + 16); a3 = *(const uint4*)(ap + 24);
      const unsigned short* bp = Bp + (kt + 1) * 64;
      b0 = *(const uint4*)bp;        b1 = *(const uint4*)(bp + 8);
      b2 = *(const uint4*)(bp + 16); b3 = *(const uint4*)(bp + 24);
    }
#pragma unroll
    for (int ks = 0; ks < 2; ++ks) {
      short8 af[4], bf[4];
#pragma unroll
      for (int fm = 0; fm < 4; ++fm)
        af[fm] = *(const short8*)&As[wr + fm * 16 + l15][ks * 32 + g * 8];
#pragma unroll
      for (int fn = 0; fn < 4; ++fn)
        bf[fn] = *(const short8*)&Bs[wc + fn * 16 + l15][ks * 32 + g * 8];
#pragma unroll
      for (int fm = 0; fm < 4; ++fm)
#pragma unroll
        for (int fn = 0; fn < 4; ++fn)
          acc[fm][fn] = __builtin_amdgcn_mfma_f32_16x16x32_bf16(
              af[fm], bf[fn], acc[fm][fn], 0, 0, 0);
    }
    if (kt < 7) __syncthreads();
  }

  if (nt < 4) {
#pragma unroll
    for (int fn = 0; fn < 4; ++fn) {
      int col = nt * 128 + wc + fn * 16 + l15;
      float bs = bq[col], uu = uvec[col], vv = vvec[col];
#pragma unroll
      for (int fm = 0; fm < 4; ++fm) {
        int row = mt * 128 + wr + fm * 16 + 4 * g;
#pragma unroll
        for (int r = 0; r < 4; ++r) {
          size_t idx = (size_t)(row + r) * 512 + col;
          float base = acc[fm][fn][r] + bs;
          QU[idx] = f2bf(base + uu);
          QV[idx] = f2bf(base + vv);
        }
      }
    }
  } else if (nt < 8) {
#pragma unroll
    for (int fn = 0; fn < 4; ++fn) {
      int col = (nt - 4) * 128 + wc + fn * 16 + l15;
#pragma unroll
      for (int fm = 0; fm < 4; ++fm) {
        int row = mt * 128 + wr + fm * 16 + 4 * g;
#pragma unroll
        for (int r = 0; r < 4; ++r)
          Kb[(size_t)(row + r) * 512 + col] = f2bf(acc[fm][fn][r]);
      }
    }
  } else if (nt < 12) {
    // V: transpose 128x128 tile through LDS, write Vt[b][h][d][s]
    __syncthreads();
    unsigned short (*T)[136] = (unsigned short(*)[136])lds;
#pragma unroll
    for (int fm = 0; fm < 4; ++fm)
#pragma unroll
      for (int fn = 0; fn < 4; ++fn)
#pragma unroll
        for (int r = 0; r < 4; ++r)
          T[wc + fn * 16 + l15][wr + fm * 16 + 4 * g + r] = f2bf(acc[fm][fn][r]);
    __syncthreads();
    int c2 = tid >> 1, sh = (tid & 1) << 6;
    int gcol = (nt - 8) * 128 + c2;
    int bb = mt >> 3, s0 = (mt & 7) * 128;
    unsigned short* op = Vt +
        ((size_t)((bb * 8 + (gcol >> 6)) * 64 + (gcol & 63))) * 1024 + s0 + sh;
#pragma unroll
    for (int j = 0; j < 8; ++j)
      *(uint4*)(op + j * 8) = *(uint4*)&T[c2][sh + j * 8];
  } else {
#pragma unroll
    for (int fn = 0; fn < 4; ++fn) {
      int col = (mt >> 4) * 128 + wc + fn * 16 + l15;
#pragma unroll
      for (int fm = 0; fm < 4; ++fm) {
        int row = (mt & 15) * 128 + wr + fm * 16 + 4 * g;
#pragma unroll
        for (int r = 0; r < 4; ++r)
          Pb[(size_t)(row + r) * 512 + col] = f2bf(acc[fm][fn][r]);
      }
    }
  }
}

// ---------- 128x128-tile GEMM, f32 out + bias (out projection) ----------
__global__ __launch_bounds__(256, 2) void gemm128f(
    const unsigned short* __restrict__ A,
    const unsigned short* __restrict__ Bt,
    const float* __restrict__ bias,
    float* __restrict__ Cf) {
  __shared__ __align__(16) unsigned short lds[2 * 128 * 72];
  unsigned short (*As)[72] = (unsigned short(*)[72])lds;
  unsigned short (*Bs)[72] = (unsigned short(*)[72])(lds + 128 * 72);
  int mt = blockIdx.x, nt = blockIdx.y;
  int tid = threadIdx.x;
  int lane = tid & 63, wave = tid >> 6;
  int l15 = lane & 15, g = lane >> 4;
  int wr = (wave >> 1) << 6, wc = (wave & 1) << 6;
  int sr = tid >> 1, sc = (tid & 1) << 5;

  const unsigned short* Ap = A + (size_t)(mt * 128 + sr) * 512 + sc;
  const unsigned short* Bp = Bt + (size_t)(nt * 128 + sr) * 512 + sc;

  uint4 a0 = *(const uint4*)Ap,        a1 = *(const uint4*)(Ap + 8);
  uint4 a2 = *(const uint4*)(Ap + 16), a3 = *(const uint4*)(Ap + 24);
  uint4 b0 = *(const uint4*)Bp,        b1 = *(const uint4*)(Bp + 8);
  uint4 b2 = *(const uint4*)(Bp + 16), b3 = *(const uint4*)(Bp + 24);

  float4v acc[4][4] = {};
  for (int kt = 0; kt < 8; ++kt) {
    *(uint4*)&As[sr][sc]      = a0; *(uint4*)&As[sr][sc + 8]  = a1;
    *(uint4*)&As[sr][sc + 16] = a2; *(uint4*)&As[sr][sc + 24] = a3;
    *(uint4*)&Bs[sr][sc]      = b0; *(uint4*)&Bs[sr][sc + 8]  = b1;
    *(uint4*)&Bs[sr][sc + 16] = b2; *(uint4*)&Bs[sr][sc + 24] = b3;
    __syncthreads();
    if (kt < 7) {
      const unsigned short* ap = Ap + (kt + 1) * 64;
      a0 = *(const uint4*)ap;        a1 = *(const uint4*)(ap + 8);
      a2 = *(const uint4*)(ap + 16); a3 = *(const uint4*)(ap + 24);
      const unsigned short* bp = Bp + (kt + 1) * 64;
      b0 = *(const uint4*)bp;        b1 = *(const uint4*)(bp + 8);
      b2 = *(const uint4*)(bp + 16); b3 = *(const uint4*)(bp + 24);
    }
#pragma unroll
    for (int ks = 0; ks < 2; ++ks) {
      short8 af[4], bf[4];
#pragma unroll
      for (int fm = 0; fm < 4; ++fm)
        af[fm] = *(const short8*)&As[wr + fm * 16 + l15][ks * 32 + g * 8];
#pragma unroll
      for (int fn = 0; fn < 4; ++fn)
        bf[fn] = *(const short8*)&Bs[wc + fn * 16 + l15][ks * 32 + g * 8];
#pragma unroll
      for (int fm = 0; fm < 4; ++fm)
#pragma unroll
        for (int fn = 0; fn < 4; ++fn)
          acc[fm][fn] = __builtin_amdgcn_mfma_f32_16x16x32_bf16(
              af[fm], bf[fn], acc[fm][fn], 0, 0, 0);
    }
    if (kt < 7) __syncthreads();
  }
#pragma unroll
  for (int fn = 0; fn < 4; ++fn) {
    int col = nt * 128 + wc + fn * 16 + l15;
    float bs = bias[col];
#pragma unroll
    for (int fm = 0; fm < 4; ++fm) {
      int row = mt * 128 + wr + fm * 16 + 4 * g;
#pragma unroll
      for (int r = 0; r < 4; ++r)
        Cf[(size_t)(row + r) * 512 + col] = acc[fm][fn][r] + bs;
    }
  }
}

// ---------- fused relative attention (R9 version, proven 68.5us) ----------
// 1D grid 1024 (XCD-swizzled), 256 threads (4 waves x 16 Q-rows).
// Circular 128-row window; window MFMA trimmed to the 5 fragments used
// (accP[k] = logical window frag C+k, C=3-wave); wave-uniform f16-packed
// shift; no-max softmax; probs in the window's dead half.
__global__ __launch_bounds__(256, 3) void attn_kernel(
    const unsigned short* __restrict__ QU,  // (B*T,512) bf16 = q+bq+u
    const unsigned short* __restrict__ QV,  // (B*T,512) bf16 = q+bq+v
    const unsigned short* __restrict__ K,   // (B*T,512) bf16
    const unsigned short* __restrict__ Vt,  // [b][h][d][s] bf16
    const unsigned short* __restrict__ P,   // (2047,512) bf16
    unsigned short* __restrict__ O) {       // (B*T,512) bf16
  __shared__ __align__(16) unsigned short k_s[64][72];
  __shared__ __align__(16) unsigned short vt_s[64][72];
  __shared__ __align__(16) unsigned short win_s[128 * 72];

  // XCD swizzle: 1024 blocks = 8 XCDs x 128 contiguous (b,h) groups
  int pid = blockIdx.x;
  int wid = (pid & 7) * 128 + (pid >> 3);
  int tt = wid & 15, h = (wid >> 4) & 7, b = wid >> 7;
  int t0 = tt * 64;
  int tid = threadIdx.x, lane = tid & 63, wave = tid >> 6;
  int lr = tid >> 2, lc = (tid & 3) << 4;
  int l15 = lane & 15, g = lane >> 4;
  int w16 = wave * 16;
  int C = 3 - wave;

  // Q fragments straight from global (held in regs for the whole block)
  short8 aqu[2], aqv[2];
  {
    size_t qoff = (size_t)(b * 1024 + t0 + w16 + l15) * 512 + h * 64 + g * 8;
    aqu[0] = *(const short8*)(QU + qoff);
    aqu[1] = *(const short8*)(QU + qoff + 32);
    aqv[0] = *(const short8*)(QV + qoff);
    aqv[1] = *(const short8*)(QV + qoff + 32);
  }

  const unsigned short* Kbase = K + (size_t)(b * 1024) * 512 + h * 64;
  const unsigned short* Vbase = Vt + (size_t)((b * 8 + h) * 64) * 1024;

  float4v accO[4] = {};
  float l_r[4] = {0.f, 0.f, 0.f, 0.f};

  // -------- prologue: stage tile 0 (K, V^T, full 128-row window) --------
  {
    const unsigned short* kp = Kbase + (size_t)lr * 512 + lc;
    uint4 k0 = *(const uint4*)kp, k1 = *(const uint4*)(kp + 8);
    const unsigned short* vp = Vbase + (size_t)lr * 1024 + lc;
    uint4 v0 = *(const uint4*)vp, v1 = *(const uint4*)(vp + 8);
    int r2 = tid >> 1, c2 = (tid & 1) << 5;
    int ph0 = (tt + 1) & 1;
    int wr = 960 - t0 + r2;                       // in [0,1087], no clamp
    const unsigned short* pp = P + (size_t)wr * 512 + h * 64 + c2;
    uint4 w0v = *(const uint4*)pp,        w1v = *(const uint4*)(pp + 8);
    uint4 w2v = *(const uint4*)(pp + 16), w3v = *(const uint4*)(pp + 24);
    *(uint4*)&k_s[lr][lc]      = k0; *(uint4*)&k_s[lr][lc + 8]  = k1;
    *(uint4*)&vt_s[lr][lc]     = v0; *(uint4*)&vt_s[lr][lc + 8] = v1;
    unsigned short* dp = &win_s[(r2 ^ (ph0 << 6)) * 72 + c2];
    *(uint4*)dp        = w0v; *(uint4*)(dp + 8)  = w1v;
    *(uint4*)(dp + 16) = w2v; *(uint4*)(dp + 24) = w3v;
  }
  __syncthreads();

  uint4 pk0, pk1, pv0, pv1, pw0, pw1;
  for (int st = 0; st < 16; ++st) {
    int ph = (st + tt + 1) & 1;
    // issue next tile's global loads (latency hides under compute)
    if (st < 15) {
      int s0n = (st + 1) * 64;
      const unsigned short* kp = Kbase + (size_t)(s0n + lr) * 512 + lc;
      pk0 = *(const uint4*)kp; pk1 = *(const uint4*)(kp + 8);
      const unsigned short* vp = Vbase + (size_t)lr * 1024 + s0n + lc;
      pv0 = *(const uint4*)vp; pv1 = *(const uint4*)(vp + 8);
      int wr = 64 * st - t0 + 1088 + lr; if (wr > 2046) wr = 2046;
      const unsigned short* pp = P + (size_t)wr * 512 + h * 64 + lc;
      pw0 = *(const uint4*)pp; pw1 = *(const uint4*)(pp + 8);
    }

    // content scores (64x64, A=QU) + the 5 needed window fragments (A=QV)
    float4v accS[4] = {}; float4v accP[5] = {};
#pragma unroll
    for (int ks = 0; ks < 2; ++ks) {
#pragma unroll
      for (int fn = 0; fn < 4; ++fn) {
        short8 bk = *(const short8*)&k_s[fn * 16 + l15][ks * 32 + g * 8];
        accS[fn] = __builtin_amdgcn_mfma_f32_16x16x32_bf16(aqu[ks], bk, accS[fn], 0, 0, 0);
      }
#pragma unroll
      for (int k = 0; k < 5; ++k) {
        int fi = (k + C) ^ (ph << 2);   // physical frag of logical C+k
        short8 bp = *(const short8*)&win_s[(fi * 16 + l15) * 72 + ks * 32 + g * 8];
        accP[k] = __builtin_amdgcn_mfma_f32_16x16x32_bf16(aqv[ks], bp, accP[k], 0, 0, 0);
      }
    }

    // relative shift via packed-f16 lane rotation (wave-uniform)
#pragma unroll
    for (int r = 0; r < 4; ++r) {
      int W0 = pk2h(accP[0][r], accP[1][r]);
      int W1 = pk2h(accP[1][r], accP[2][r]);
      int W2 = pk2h(accP[2][r], accP[3][r]);
      int W3 = pk2h(accP[3][r], accP[4][r]);
      int srcLane = (lane & 48) | ((l15 - 4 * g - r - 1) & 15);
      int carry = (l15 >= 4 * g + r + 1);
      int x0 = __shfl(W0, srcLane), x1 = __shfl(W1, srcLane);
      int x2 = __shfl(W2, srcLane), x3 = __shfl(W3, srcLane);
      int wa = carry ? x1 : x0;
      int wb = carry ? x3 : x2;
      accS[0][r] = (accS[0][r] + h_lo(wa)) * 0.125f;
      accS[1][r] = (accS[1][r] + h_hi(wa)) * 0.125f;
      accS[2][r] = (accS[2][r] + h_lo(wb)) * 0.125f;
      accS[3][r] = (accS[3][r] + h_hi(wb)) * 0.125f;
    }

    __syncthreads();     // B3: all waves done reading window/k_s

    // no-max softmax: e = exp(s - 8), probs -> dead half, l accumulates
    int pbase = (ph << 6) + w16;
#pragma unroll
    for (int r = 0; r < 4; ++r) {
      float rs = 0.f;
#pragma unroll
      for (int fn = 0; fn < 4; ++fn) {
        float e = __expf(accS[fn][r] - 8.0f);
        win_s[(pbase + 4 * g + r) * 72 + fn * 16 + l15] = f2bf(e);
        rs += e;
      }
      l_r[r] += rs;
    }

    // PV: accO += P @ V  (A-frag: own probs rows; B-frag: vt_s)
#pragma unroll
    for (int ks = 0; ks < 2; ++ks) {
      short8 ap = *(const short8*)&win_s[(pbase + l15) * 72 + ks * 32 + g * 8];
#pragma unroll
      for (int fn = 0; fn < 4; ++fn) {
        short8 bv = *(const short8*)&vt_s[fn * 16 + l15][ks * 32 + g * 8];
        accO[fn] = __builtin_amdgcn_mfma_f32_16x16x32_bf16(ap, bv, accO[fn], 0, 0, 0);
      }
    }

    if (st < 15) {
      __syncthreads();   // B1: probs + vt_s reads done everywhere
      // STORET: K, V^T, and the 64 NEW window rows into the dead half
      *(uint4*)&k_s[lr][lc]      = pk0; *(uint4*)&k_s[lr][lc + 8]  = pk1;
      *(uint4*)&vt_s[lr][lc]     = pv0; *(uint4*)&vt_s[lr][lc + 8] = pv1;
      unsigned short* dp = &win_s[(lr + (ph << 6)) * 72 + lc];
      *(uint4*)dp = pw0; *(uint4*)(dp + 8) = pw1;
      __syncthreads();   // B2: staging visible
    }
  }

  // epilogue: reduce l across the 16-lane row group, then O / l -> bf16
  float rinv[4];
#pragma unroll
  for (int r = 0; r < 4; ++r) {
    float l = l_r[r];
    l += __shfl_xor(l, 1); l += __shfl_xor(l, 2);
    l += __shfl_xor(l, 4); l += __shfl_xor(l, 8);
    rinv[r] = 1.0f / l;
  }
#pragma unroll
  for (int fn = 0; fn < 4; ++fn) {
    int dcol = fn * 16 + l15;
#pragma unroll
    for (int r = 0; r < 4; ++r) {
      int row = t0 + w16 + 4 * g + r;
      float o = accO[fn][r] * rinv[r];
      O[(size_t)(b * 1024 + row) * 512 + h * 64 + dcol] = f2bf(o);
    }
  }
}

// ---------- host ----------
extern "C" void kernel_launch(void* const* d_in, const int* in_sizes, int n_in,
                              void* d_out, int out_size, void* d_ws, size_t ws_size,
                              hipStream_t stream) {
  const float* x       = (const float*)d_in[0];
  const float* pos_emb = (const float*)d_in[1];
  const float* Wq      = (const float*)d_in[2];
  const float* bq      = (const float*)d_in[3];
  const float* Wk      = (const float*)d_in[4];
  const float* Wv      = (const float*)d_in[5];
  const float* Wp      = (const float*)d_in[6];
  const float* Wo      = (const float*)d_in[7];
  const float* bo      = (const float*)d_in[8];
  const float* u       = (const float*)d_in[9];
  const float* v       = (const float*)d_in[10];

  char* ws = (char*)d_ws;
  unsigned short* xb   = (unsigned short*)ws; ws += (size_t)8192 * 512 * 2;
  unsigned short* peb  = (unsigned short*)ws; ws += (size_t)2048 * 512 * 2;
  unsigned short* wqkv = (unsigned short*)ws; ws += (size_t)5 * 512 * 512 * 2;
  unsigned short* qub  = (unsigned short*)ws; ws += (size_t)8192 * 512 * 2;
  unsigned short* qvb  = (unsigned short*)ws; ws += (size_t)8192 * 512 * 2;
  unsigned short* kb   = (unsigned short*)ws; ws += (size_t)8192 * 512 * 2;
  unsigned short* vtb  = (unsigned short*)ws; ws += (size_t)8192 * 512 * 2;
  unsigned short* pb   = (unsigned short*)ws; ws += (size_t)2048 * 512 * 2;
  unsigned short* attb = (unsigned short*)ws; ws += (size_t)8192 * 512 * 2;

  cvt_bf16_kernel<<<4096, 256, 0, stream>>>(x, xb, 1048576);
  cvt_bf16_kernel<<<1024, 256, 0, stream>>>(pos_emb, peb, 262016);
  transpose_cvt5_kernel<<<dim3(64, 5), 256, 0, stream>>>(Wq, Wk, Wv, Wp, Wo, wqkv);
  unsigned short* wpt_p = wqkv + (size_t)3 * 262144;
  unsigned short* wot_p = wqkv + (size_t)4 * 262144;

  qkv_gemm128<<<dim3(64, 13), 256, 0, stream>>>(xb, wqkv, bq, u, v,
                                                qub, qvb, kb, vtb,
                                                peb, wpt_p, pb);

  attn_kernel<<<1024, 256, 0, stream>>>(qub, qvb, kb, vtb, pb, attb);

  gemm128f<<<dim3(64, 4), 256, 0, stream>>>(attb, wot_p, bo, (float*)d_out);
}